// Round 1
// baseline (557.652 us; speedup 1.0000x reference)
//
#include <hip/hip_runtime.h>
#include <hip/hip_bf16.h>

typedef __attribute__((ext_vector_type(8))) short bf16x8;   // 8 bf16 in 4 VGPRs
typedef __attribute__((ext_vector_type(4))) float f32x4;

#define WDIM 512
#define CIN 128
#define COUT 128
#define NRES 32
#define NSP 32768          // 32^3
#define NTAPS 27

// conv spatial tile: 4 x 8 x 8 = 256 outputs per block
#define TZ 4
#define TY 8
#define TXW 8
#define HVOL 600           // halo 6*10*10
#define CCH 32             // cin chunk per stage
#define NCC 4              // 128/32
#define CSTR 40            // LDS row stride in bf16 elems (32 + 8 pad = 80 B, 16B-aligned)

// ---------------- kernel 1: styles = w @ (aw/sqrt(512)).T + ab ----------------
__global__ void k_styles(const float* __restrict__ w,
                         const float* __restrict__ aw,
                         const float* __restrict__ ab,
                         float* __restrict__ styles) {
  int b = blockIdx.x;      // 8
  int c = threadIdx.x;     // 128
  const float4* wr = (const float4*)(w + (size_t)b * WDIM);
  const float4* ar = (const float4*)(aw + (size_t)c * WDIM);
  float s = 0.f;
#pragma unroll 8
  for (int k = 0; k < WDIM / 4; k++) {
    float4 wv = wr[k], av = ar[k];
    s += wv.x * av.x + wv.y * av.y + wv.z * av.z + wv.w * av.w;
  }
  styles[b * CIN + c] = s * 0.04419417382415922f + ab[c];  // 1/sqrt(512)
}

// -------- kernel 2: modulate+demodulate -> bf16 wmod[b][tap][cout][cin] --------
__global__ void k_wmod(const float* __restrict__ weight,
                       const float* __restrict__ styles,
                       __hip_bfloat16* __restrict__ wmod) {
  int b = blockIdx.x >> 7;
  int co = blockIdx.x & 127;
  __shared__ float st[CIN];
  __shared__ float red[4];
  int tid = threadIdx.x;   // 256
  if (tid < CIN) st[tid] = styles[b * CIN + tid];
  __syncthreads();
  const float* wr = weight + (size_t)co * (CIN * NTAPS);  // [cin][27] for this cout
  float ss = 0.f;
  for (int o = tid; o < CIN * NTAPS; o += 256) {
    float v = wr[o] * st[o / NTAPS];
    ss += v * v;
  }
#pragma unroll
  for (int off = 32; off > 0; off >>= 1) ss += __shfl_down(ss, off);
  if ((tid & 63) == 0) red[tid >> 6] = ss;
  __syncthreads();
  float d = rsqrtf(red[0] + red[1] + red[2] + red[3] + 1e-8f);
  // write pass: o = t*128 + cin -> coalesced bf16 stores over cin
  for (int o = tid; o < CIN * NTAPS; o += 256) {
    int t = o >> 7;
    int cin = o & 127;
    float v = wr[cin * NTAPS + t] * st[cin] * d;
    wmod[((size_t)(b * NTAPS + t) * COUT + co) * CIN + cin] = __float2bfloat16(v);
  }
}

// ---------------- kernel 3: implicit-GEMM conv + bias + lrelu*sqrt(2) ----------------
// block: 512 thr (8 waves, 2 cout-groups x 4 spatial-groups), tile M=128(cout) x N=256(spatial)
__global__ __launch_bounds__(512)
void k_conv(const float* __restrict__ x,
            const __hip_bfloat16* __restrict__ wmod,
            const float* __restrict__ bias,
            float* __restrict__ out) {
  __shared__ int voff[HVOL];
  __shared__ __align__(16) __hip_bfloat16 xs[HVOL * CSTR];

  // (tz*100 + ty*10 + tx) * 5  (bf16x8-unit LDS offsets per tap)
  static const int TOFF5[NTAPS] = {
      0,    5,    10,   50,   55,   60,   100,  105,  110,
      500,  505,  510,  550,  555,  560,  600,  605,  610,
      1000, 1005, 1010, 1050, 1055, 1060, 1100, 1105, 1110};

  int tid = threadIdx.x;
  int blk = blockIdx.x;
  int b = blk >> 7;
  int tile = blk & 127;            // 8 z-tiles * 4 y-tiles * 4 x-tiles
  int z0 = (tile >> 4) * TZ;
  int y0 = ((tile >> 2) & 3) * TY;
  int x0 = (tile & 3) * TXW;

  // halo -> global-offset table (-1 = zero pad)
  for (int h = tid; h < HVOL; h += 512) {
    int hz = h / 100;
    int r = h - hz * 100;
    int hy = r / 10;
    int hx = r - hy * 10;
    int zz = z0 + hz - 1, yy = y0 + hy - 1, xx = x0 + hx - 1;
    voff[h] = ((unsigned)zz < NRES && (unsigned)yy < NRES && (unsigned)xx < NRES)
                  ? (zz * 1024 + yy * 32 + xx)
                  : -1;
  }

  int lane = tid & 63;
  int wid = tid >> 6;
  int wm = wid >> 2;   // 0..1  cout group (64 rows)
  int wn = wid & 3;    // 0..3  spatial group (64 cols)
  int l15 = lane & 15;
  int g = lane >> 4;

  int hb5[4], sp[4];
#pragma unroll
  for (int ni = 0; ni < 4; ni++) {
    int n = wn * 64 + ni * 16 + l15;           // spatial in [0,256)
    int dz = n >> 6, dy = (n >> 3) & 7, dx = n & 7;
    hb5[ni] = (dz * 100 + dy * 10 + dx) * 5;   // LDS bf16x8 units
    sp[ni] = dz * 1024 + dy * 32 + dx;         // global spatial offset
  }
  int arowv[4];
#pragma unroll
  for (int mi = 0; mi < 4; mi++)
    arowv[mi] = (wm * 64 + mi * 16 + l15) * (CIN / 8) + g;  // bf16x8 units

  f32x4 acc[4][4];
#pragma unroll
  for (int mi = 0; mi < 4; mi++)
#pragma unroll
    for (int ni = 0; ni < 4; ni++) acc[mi][ni] = (f32x4){0.f, 0.f, 0.f, 0.f};

  const float* xb = x + (size_t)b * CIN * NSP;
  const __hip_bfloat16* wb = wmod + (size_t)b * NTAPS * COUT * CIN;
  const bf16x8* bp = (const bf16x8*)xs;

#pragma unroll 1
  for (int cc = 0; cc < NCC; cc++) {
    __syncthreads();  // xs free (also covers voff on cc==0)
    {
      // stage halo x-chunk (f32 -> bf16), LDS transposed: xs[h][cin_local]
      const float* xg = xb + (size_t)cc * CCH * NSP;
      int rem = tid, cin_l = 0;
      for (int idx = tid; idx < HVOL * CCH; idx += 512) {
        int off = voff[rem];
        float v = (off >= 0) ? xg[(size_t)cin_l * NSP + off] : 0.f;
        xs[rem * CSTR + cin_l] = __float2bfloat16(v);
        rem += 512;
        if (rem >= HVOL) { rem -= HVOL; cin_l++; }
      }
    }
    __syncthreads();

    for (int t = 0; t < NTAPS; t++) {
      const bf16x8* ap = (const bf16x8*)(wb + (size_t)t * COUT * CIN + cc * CCH);
      int tof = TOFF5[t];
      bf16x8 a[4], bv[4];
#pragma unroll
      for (int mi = 0; mi < 4; mi++) a[mi] = ap[arowv[mi]];        // W from L2
#pragma unroll
      for (int ni = 0; ni < 4; ni++) bv[ni] = bp[hb5[ni] + tof + g];  // X from LDS
#pragma unroll
      for (int mi = 0; mi < 4; mi++)
#pragma unroll
        for (int ni = 0; ni < 4; ni++)
          acc[mi][ni] = __builtin_amdgcn_mfma_f32_16x16x32_bf16(
              a[mi], bv[ni], acc[mi][ni], 0, 0, 0);
    }
  }

  // epilogue: D row = cout = wm*64 + mi*16 + g*4 + r ; col = spatial n
  size_t obase0 = (size_t)(b * COUT + wm * 64 + g * 4) * NSP +
                  (size_t)(z0 * 1024 + y0 * 32 + x0);
#pragma unroll
  for (int mi = 0; mi < 4; mi++) {
    int c4 = wm * 64 + mi * 16 + g * 4;
    float4 bsv = *(const float4*)(bias + c4);
    float bs[4] = {bsv.x, bsv.y, bsv.z, bsv.w};
#pragma unroll
    for (int ni = 0; ni < 4; ni++) {
#pragma unroll
      for (int r = 0; r < 4; r++) {
        float v = acc[mi][ni][r] + bs[r];
        v = (v >= 0.f ? v : v * 0.2f) * 1.41421356237309515f;
        out[obase0 + (size_t)(mi * 16 + r) * NSP + sp[ni]] = v;
      }
    }
  }
}

extern "C" void kernel_launch(void* const* d_in, const int* in_sizes, int n_in,
                              void* d_out, int out_size, void* d_ws, size_t ws_size,
                              hipStream_t stream) {
  const float* x      = (const float*)d_in[0];
  const float* w      = (const float*)d_in[1];
  const float* weight = (const float*)d_in[2];
  const float* aw     = (const float*)d_in[3];
  const float* ab     = (const float*)d_in[4];
  const float* bias   = (const float*)d_in[5];
  float* out = (float*)d_out;

  // ws layout: [0,4096) styles f32[8][128]; [4096, 4096+7077888) wmod bf16[8][27][128][128]
  float* styles = (float*)d_ws;
  __hip_bfloat16* wmod = (__hip_bfloat16*)((char*)d_ws + 4096);

  k_styles<<<8, 128, 0, stream>>>(w, aw, ab, styles);
  k_wmod<<<8 * 128, 256, 0, stream>>>(weight, styles, wmod);
  k_conv<<<8 * 128, 512, 0, stream>>>(x, wmod, bias, out);
}